// Round 5
// baseline (346.660 us; speedup 1.0000x reference)
//
#include <hip/hip_runtime.h>
#include <hip/hip_bf16.h>

#define Bn 2
#define Tn 2048
#define Cn 1024
#define Hn 16
#define Dn 64
#define Mrows (Bn * Tn)   // 4096

typedef __attribute__((ext_vector_type(8))) short short8;
typedef __attribute__((ext_vector_type(4))) float f32x4;

typedef const __attribute__((address_space(1))) unsigned int* gas_ptr;
typedef __attribute__((address_space(3))) unsigned int* las_ptr;

__device__ __forceinline__ unsigned short f2b(float f) {
  unsigned int u = __builtin_bit_cast(unsigned int, f);
  return (unsigned short)((u + 0x7fffu + ((u >> 16) & 1u)) >> 16);
}

// ---------------- LayerNorm: f32 in -> bf16 out ----------------
__global__ __launch_bounds__(256) void ln_kernel(const float* __restrict__ x,
                                                 const float* __restrict__ w,
                                                 const float* __restrict__ b,
                                                 unsigned short* __restrict__ out) {
  const int row = blockIdx.x;
  const int t = threadIdx.x;
  const float4 v = *reinterpret_cast<const float4*>(x + (size_t)row * Cn + t * 4);
  float s = v.x + v.y + v.z + v.w;
  float s2 = v.x * v.x + v.y * v.y + v.z * v.z + v.w * v.w;
#pragma unroll
  for (int m = 1; m < 64; m <<= 1) { s += __shfl_xor(s, m); s2 += __shfl_xor(s2, m); }
  __shared__ float ls[4], ls2[4];
  if ((t & 63) == 0) { ls[t >> 6] = s; ls2[t >> 6] = s2; }
  __syncthreads();
  s  = ls[0] + ls[1] + ls[2] + ls[3];
  s2 = ls2[0] + ls2[1] + ls2[2] + ls2[3];
  const float mu = s * (1.0f / Cn);
  const float rstd = rsqrtf(s2 * (1.0f / Cn) - mu * mu + 1e-5f);
  const float4 wv = *reinterpret_cast<const float4*>(w + t * 4);
  const float4 bv = *reinterpret_cast<const float4*>(b + t * 4);
  unsigned short o[4];
  o[0] = f2b((v.x - mu) * rstd * wv.x + bv.x);
  o[1] = f2b((v.y - mu) * rstd * wv.y + bv.y);
  o[2] = f2b((v.z - mu) * rstd * wv.z + bv.z);
  o[3] = f2b((v.w - mu) * rstd * wv.w + bv.w);
  *reinterpret_cast<uint2*>(out + (size_t)row * Cn + t * 4) = *reinterpret_cast<uint2*>(o);
}

// ---------------- Transpose + f32->bf16: W[K][N] -> Wt[N][K] ----------------
__global__ __launch_bounds__(256) void transpose_bf16_kernel(const float* __restrict__ W,
                                                             unsigned short* __restrict__ Wt,
                                                             int K, int N) {
  __shared__ float tile[32][33];
  const int n0 = blockIdx.x * 32, k0 = blockIdx.y * 32;
  const int tx = threadIdx.x & 31, ty = threadIdx.x >> 5;  // ty 0..7
#pragma unroll
  for (int r = 0; r < 4; r++)
    tile[ty + r * 8][tx] = W[(size_t)(k0 + ty + r * 8) * N + n0 + tx];
  __syncthreads();
#pragma unroll
  for (int r = 0; r < 4; r++)
    Wt[(size_t)(n0 + ty + r * 8) * K + k0 + tx] = f2b(tile[tx][ty + r * 8]);
}

// ---------------- bf16 GEMM: C[M][N] = A[M][K] @ Bt[N][K]^T + bias, epilogues ----------------
// T4 pipeline: 3 LDS buffers, 2 staged tiles in flight, counted vmcnt(4) (never 0 in
// steady state). Ordering proof:
//   read tile t  : end of iter t-1 does vmcnt(4) [leaves only tile t+1's 4 loads] then
//                  s_barrier -> ALL waves' tile-t loads landed -> iter t ds_read safe.
//   overwrite buf: stage(t+2) writes buf[(t+2)%3]=buf[(t-1)%3], last ds_read at iter t-1
//                  whose lgkmcnt(0) precedes the iter t-1 end barrier -> issue-after ok.
// EP=0: out bf16 = v+bias; EP=1: out f32 = v+bias+res; EP=2: out bf16 = gelu(v+bias)
template <int EP>
__global__ __launch_bounds__(256) void gemm_kernel(const unsigned short* __restrict__ A,
                                                   const unsigned short* __restrict__ Bt,
                                                   const float* __restrict__ bias,
                                                   const float* res, void* out,
                                                   int M, int N, int K, int nx) {
  __shared__ unsigned short As[3][128 * 32];
  __shared__ unsigned short Bs[3][128 * 32];
  const int tid = threadIdx.x;
  const int lane = tid & 63, w = tid >> 6;
  const int wm = w >> 1, wn = w & 1;
  const int l15 = lane & 15, l4 = lane >> 4;

  // XCD-aware bijective swizzle (all call sites have gridDim.x % 8 == 0).
  const int nwg = gridDim.x;
  int wg = blockIdx.x;
  wg = (wg & 7) * (nwg >> 3) + (wg >> 3);
  const int tile_m = (wg / nx) * 128;
  const int tile_n = (wg % nx) * 128;

  f32x4 acc[4][4] = {};

  // chunk = r*4 + c16 (r 0..127, c16 0..3 16B-chunks); LDS linear == chunk order.
  const int cbase0 = w * 64 + lane;
  auto stage = [&](int buf, int k0) {   // 4 VMEM insts per wave
#pragma unroll
    for (int i = 0; i < 2; i++) {
      const int chunk = i * 256 + cbase0;
      const int r = chunk >> 2, c = (chunk & 3) * 8;
      __builtin_amdgcn_global_load_lds(
          (gas_ptr)&A[(size_t)(tile_m + r) * K + k0 + c],
          (las_ptr)&As[buf][(i * 256 + w * 64) * 8], 16, 0, 0);
      __builtin_amdgcn_global_load_lds(
          (gas_ptr)&Bt[(size_t)(tile_n + r) * K + k0 + c],
          (las_ptr)&Bs[buf][(i * 256 + w * 64) * 8], 16, 0, 0);
    }
  };

  // prologue: tiles 0,1 staged; wait tile 0 only (tile 1 stays in flight)
  stage(0, 0);
  stage(1, 32);
  asm volatile("s_waitcnt vmcnt(4)" ::: "memory");
  __builtin_amdgcn_s_barrier();
  __builtin_amdgcn_sched_barrier(0);

  const int nt = K >> 5;   // >= 32 for all call sites
  for (int t = 0; t < nt; ++t) {
    if (t + 2 < nt) stage((t + 2) % 3, (t + 2) * 32);
    __builtin_amdgcn_sched_barrier(0);

    const int cur = t % 3;
    short8 a[4], b[4];
#pragma unroll
    for (int mi = 0; mi < 4; mi++)
      a[mi] = *reinterpret_cast<const short8*>(&As[cur][(wm * 64 + mi * 16 + l15) * 32 + l4 * 8]);
#pragma unroll
    for (int ni = 0; ni < 4; ni++)
      b[ni] = *reinterpret_cast<const short8*>(&Bs[cur][(wn * 64 + ni * 16 + l15) * 32 + l4 * 8]);
    asm volatile("s_waitcnt lgkmcnt(0)" ::: "memory");
    __builtin_amdgcn_sched_barrier(0);               // rule #18: keep MFMA below the wait

#pragma unroll
    for (int mi = 0; mi < 4; mi++)
#pragma unroll
      for (int ni = 0; ni < 4; ni++)
        acc[mi][ni] = __builtin_amdgcn_mfma_f32_16x16x32_bf16(a[mi], b[ni], acc[mi][ni], 0, 0, 0);
    __builtin_amdgcn_sched_barrier(0);

    // drain tile t+1 (leave tile t+2's 4 loads in flight), then barrier
    if (t + 2 < nt) {
      asm volatile("s_waitcnt vmcnt(4)" ::: "memory");
    } else {
      asm volatile("s_waitcnt vmcnt(0)" ::: "memory");
    }
    __builtin_amdgcn_s_barrier();
    __builtin_amdgcn_sched_barrier(0);
  }

#pragma unroll
  for (int ni = 0; ni < 4; ni++) {
    const int col = tile_n + wn * 64 + ni * 16 + l15;
    const float bv = bias[col];
#pragma unroll
    for (int mi = 0; mi < 4; mi++) {
#pragma unroll
      for (int r = 0; r < 4; r++) {
        const int row = tile_m + wm * 64 + mi * 16 + l4 * 4 + r;
        const size_t idx = (size_t)row * N + col;
        float v = acc[mi][ni][r] + bv;
        if (EP == 0) {
          ((unsigned short*)out)[idx] = f2b(v);
        } else if (EP == 1) {
          ((float*)out)[idx] = v + res[idx];
        } else {
          float g = 0.5f * v * (1.0f + erff(v * 0.70710678118f));
          ((unsigned short*)out)[idx] = f2b(g);
        }
      }
    }
  }
}

// ---------------- Strided-sparse flash attention ----------------
// qkv: bf16 [B,T,3C]; y: bf16 [B,T,C]. grid (T/128, B*H), 256 thr (4 waves x 32 q-rows).
__global__ __launch_bounds__(256) void attn_kernel(const unsigned short* __restrict__ qkv,
                                                   unsigned short* __restrict__ y) {
  const int qt = blockIdx.x;
  const int bh = blockIdx.y;
  const int bb = bh >> 4, hh = bh & 15;
  const int q0 = qt * 128;
  const int tid = threadIdx.x;
  const int lane = tid & 63, w = tid >> 6;
  const int l15 = lane & 15, l4 = lane >> 4;

  __shared__ unsigned short Qs[128 * 64];
  __shared__ unsigned short Ks[64 * 64];
  __shared__ unsigned short Vt[64 * 72];
  __shared__ unsigned short Ps[4][32 * 72];

  const size_t base = (size_t)bb * Tn * (3 * Cn) + hh * 64;

  // stage Q (XOR-swizzled 16B chunks within 128B rows)
#pragma unroll
  for (int i = 0; i < 4; i++) {
    const int chunk = i * 256 + tid;          // 0..1023
    const int r = chunk >> 3, c = chunk & 7;
    uint4 v = *reinterpret_cast<const uint4*>(&qkv[base + (size_t)(q0 + r) * (3 * Cn) + c * 8]);
    *reinterpret_cast<uint4*>(&Qs[r * 64 + ((c ^ (r & 7)) * 8)]) = v;
  }
  __syncthreads();
  // hoist this wave's Q fragments
  short8 qf[2][2];
#pragma unroll
  for (int mi = 0; mi < 2; mi++)
#pragma unroll
    for (int ks = 0; ks < 2; ks++) {
      const int r = w * 32 + mi * 16 + l15;
      const int c = ks * 4 + l4;
      qf[mi][ks] = *reinterpret_cast<const short8*>(&Qs[r * 64 + ((c ^ (r & 7)) * 8)]);
    }

  f32x4 acc_o[2][4] = {};
  float mrow[2][4], lrow[2][4];
#pragma unroll
  for (int mi = 0; mi < 2; mi++)
#pragma unroll
    for (int r = 0; r < 4; r++) { mrow[mi][r] = -1e30f; lrow[mi][r] = 0.0f; }

  const int nfar = (qt >= 1) ? (qt - 1) : 0;            // far tiles: 64 even keys each
  const int nstart = (q0 >= 128) ? (q0 - 128) : 0;      // near region start
  const int ntiles = nfar + (q0 + 128 - nstart) / 64;

  for (int it = 0; it < ntiles; it++) {
    const bool far = (it < nfar);
    const int kbase = far ? it * 128 : nstart + (it - nfar) * 64;
    const int kstride = far ? 2 : 1;

    __syncthreads();
    // stage K (swizzled) and V (transposed, padded) — far tiles gather even keys
#pragma unroll
    for (int i = 0; i < 2; i++) {
      const int chunk = i * 256 + tid;        // 0..511
      const int r = chunk >> 3, c = chunk & 7;
      const int key = kbase + r * kstride;
      uint4 kv = *reinterpret_cast<const uint4*>(&qkv[base + Cn + (size_t)key * (3 * Cn) + c * 8]);
      *reinterpret_cast<uint4*>(&Ks[r * 64 + ((c ^ (r & 7)) * 8)]) = kv;
      uint4 vv = *reinterpret_cast<const uint4*>(&qkv[base + 2 * Cn + (size_t)key * (3 * Cn) + c * 8]);
      unsigned short tmp[8];
      *reinterpret_cast<uint4*>(tmp) = vv;
#pragma unroll
      for (int j = 0; j < 8; j++) Vt[(c * 8 + j) * 72 + r] = tmp[j];
    }
    __syncthreads();

    // S = Q K^T
    f32x4 s[2][4] = {};
#pragma unroll
    for (int ni = 0; ni < 4; ni++) {
#pragma unroll
      for (int ks = 0; ks < 2; ks++) {
        const int r = ni * 16 + l15;
        const int c = ks * 4 + l4;
        short8 kf = *reinterpret_cast<const short8*>(&Ks[r * 64 + ((c ^ (r & 7)) * 8)]);
#pragma unroll
        for (int mi = 0; mi < 2; mi++)
          s[mi][ni] = __builtin_amdgcn_mfma_f32_16x16x32_bf16(qf[mi][ks], kf, s[mi][ni], 0, 0, 0);
      }
    }

    // scale + mask (near tiles only; far tiles are all-allowed even keys)
#pragma unroll
    for (int mi = 0; mi < 2; mi++)
#pragma unroll
      for (int ni = 0; ni < 4; ni++) {
        const int j = kbase + (ni * 16 + l15) * kstride;
#pragma unroll
        for (int r = 0; r < 4; r++) {
          const int iq = q0 + w * 32 + mi * 16 + l4 * 4 + r;
          float v = s[mi][ni][r] * 0.125f;
          if (!far) {
            const bool ok = (j <= iq) && ((j >= iq - 4) || ((j & 1) == 0));
            v = ok ? v : -1e30f;
          }
          s[mi][ni][r] = v;
        }
      }

    // online softmax
#pragma unroll
    for (int mi = 0; mi < 2; mi++)
#pragma unroll
      for (int r = 0; r < 4; r++) {
        float tm = fmaxf(fmaxf(s[mi][0][r], s[mi][1][r]), fmaxf(s[mi][2][r], s[mi][3][r]));
        tm = fmaxf(tm, __shfl_xor(tm, 1));
        tm = fmaxf(tm, __shfl_xor(tm, 2));
        tm = fmaxf(tm, __shfl_xor(tm, 4));
        tm = fmaxf(tm, __shfl_xor(tm, 8));
        const float mnew = fmaxf(mrow[mi][r], tm);
        const float alpha = __expf(mrow[mi][r] - mnew);
        mrow[mi][r] = mnew;
        lrow[mi][r] *= alpha;
#pragma unroll
        for (int nd = 0; nd < 4; nd++) acc_o[mi][nd][r] *= alpha;
        float rs = 0.0f;
#pragma unroll
        for (int ni = 0; ni < 4; ni++) {
          const float p = __expf(s[mi][ni][r] - mnew);
          s[mi][ni][r] = p;
          rs += p;
        }
        rs += __shfl_xor(rs, 1); rs += __shfl_xor(rs, 2);
        rs += __shfl_xor(rs, 4); rs += __shfl_xor(rs, 8);
        lrow[mi][r] += rs;
      }

    // P -> LDS (C-layout to A-layout round trip, wave-private, padded stride 72)
#pragma unroll
    for (int mi = 0; mi < 2; mi++)
#pragma unroll
      for (int ni = 0; ni < 4; ni++)
#pragma unroll
        for (int r = 0; r < 4; r++)
          Ps[w][(mi * 16 + l4 * 4 + r) * 72 + ni * 16 + l15] = f2b(s[mi][ni][r]);

    // O += P @ V
#pragma unroll
    for (int ks = 0; ks < 2; ks++) {
      short8 pf[2];
#pragma unroll
      for (int mi = 0; mi < 2; mi++)
        pf[mi] = *reinterpret_cast<const short8*>(&Ps[w][(mi * 16 + l15) * 72 + ks * 32 + l4 * 8]);
#pragma unroll
      for (int nd = 0; nd < 4; nd++) {
        short8 vf = *reinterpret_cast<const short8*>(&Vt[(nd * 16 + l15) * 72 + ks * 32 + l4 * 8]);
#pragma unroll
        for (int mi = 0; mi < 2; mi++)
          acc_o[mi][nd] = __builtin_amdgcn_mfma_f32_16x16x32_bf16(pf[mi], vf, acc_o[mi][nd], 0, 0, 0);
      }
    }
  }

  // normalize + write y
#pragma unroll
  for (int mi = 0; mi < 2; mi++)
#pragma unroll
    for (int r = 0; r < 4; r++) {
      const float inv = 1.0f / lrow[mi][r];
      const int row = q0 + w * 32 + mi * 16 + l4 * 4 + r;
#pragma unroll
      for (int nd = 0; nd < 4; nd++) {
        const int col = nd * 16 + l15;
        y[((size_t)bb * Tn + row) * Cn + hh * 64 + col] = f2b(acc_o[mi][nd][r] * inv);
      }
    }
}

// ---------------- launch ----------------
extern "C" void kernel_launch(void* const* d_in, const int* in_sizes, int n_in,
                              void* d_out, int out_size, void* d_ws, size_t ws_size,
                              hipStream_t stream) {
  const float* x           = (const float*)d_in[0];
  const float* ln1_w       = (const float*)d_in[1];
  const float* ln1_b       = (const float*)d_in[2];
  const float* c_attn_w    = (const float*)d_in[3];
  const float* c_attn_b    = (const float*)d_in[4];
  const float* attn_proj_w = (const float*)d_in[5];
  const float* attn_proj_b = (const float*)d_in[6];
  const float* ln2_w       = (const float*)d_in[7];
  const float* ln2_b       = (const float*)d_in[8];
  const float* fc_w        = (const float*)d_in[9];
  const float* fc_b        = (const float*)d_in[10];
  const float* mlp_proj_w  = (const float*)d_in[11];
  const float* mlp_proj_b  = (const float*)d_in[12];
  float* out = (float*)d_out;

  char* ws = (char*)d_ws;
  unsigned short* wT1 = (unsigned short*)(ws);                     // [3072][1024] 6291456 B
  unsigned short* wT2 = (unsigned short*)(ws + 6291456);           // [1024][1024] 2097152 B
  unsigned short* wT3 = (unsigned short*)(ws + 8388608);           // [4096][1024] 8388608 B
  unsigned short* wT4 = (unsigned short*)(ws + 16777216);          // [1024][4096] 8388608 B
  unsigned short* h   = (unsigned short*)(ws + 25165824);          // [4096][1024] 8388608 B (h / h2)
  unsigned short* qkv = (unsigned short*)(ws + 33554432);          // [4096][3072] (reused as [4096][4096]) 33554432 B
  unsigned short* yb  = (unsigned short*)(ws + 67108864);          // [4096][1024] 8388608 B

  // weight transposes (f32 -> bf16, [K][N] -> [N][K])
  transpose_bf16_kernel<<<dim3(3072 / 32, 1024 / 32), 256, 0, stream>>>(c_attn_w, wT1, 1024, 3072);
  transpose_bf16_kernel<<<dim3(1024 / 32, 1024 / 32), 256, 0, stream>>>(attn_proj_w, wT2, 1024, 1024);
  transpose_bf16_kernel<<<dim3(4096 / 32, 1024 / 32), 256, 0, stream>>>(fc_w, wT3, 1024, 4096);
  transpose_bf16_kernel<<<dim3(1024 / 32, 4096 / 32), 256, 0, stream>>>(mlp_proj_w, wT4, 4096, 1024);

  // LN1
  ln_kernel<<<Mrows, 256, 0, stream>>>(x, ln1_w, ln1_b, h);
  // qkv = h @ c_attn_w + b   [4096, 3072]
  gemm_kernel<0><<<(3072 / 128) * (Mrows / 128), 256, 0, stream>>>(h, wT1, c_attn_b, nullptr, qkv, Mrows, 3072, 1024, 3072 / 128);
  // attention -> y
  attn_kernel<<<dim3(Tn / 128, Bn * Hn), 256, 0, stream>>>(qkv, yb);
  // x1 = x + y @ attn_proj_w + b  -> d_out (f32)
  gemm_kernel<1><<<(1024 / 128) * (Mrows / 128), 256, 0, stream>>>(yb, wT2, attn_proj_b, x, out, Mrows, 1024, 1024, 1024 / 128);
  // LN2 on x1
  ln_kernel<<<Mrows, 256, 0, stream>>>(out, ln2_w, ln2_b, h);
  // a = gelu(h2 @ fc_w + b)   [4096, 4096]
  gemm_kernel<2><<<(4096 / 128) * (Mrows / 128), 256, 0, stream>>>(h, wT3, fc_b, nullptr, qkv, Mrows, 4096, 1024, 4096 / 128);
  // out = x1 + a @ mlp_proj_w + b
  gemm_kernel<1><<<(1024 / 128) * (Mrows / 128), 256, 0, stream>>>(qkv, wT4, mlp_proj_b, out, out, Mrows, 1024, 4096, 1024 / 128);
}

// Round 6
// 330.177 us; speedup vs baseline: 1.0499x; 1.0499x over previous
//
#include <hip/hip_runtime.h>
#include <hip/hip_bf16.h>

#define Bn 2
#define Tn 2048
#define Cn 1024
#define Hn 16
#define Dn 64
#define Mrows (Bn * Tn)   // 4096

typedef __attribute__((ext_vector_type(8))) short short8;
typedef __attribute__((ext_vector_type(4))) float f32x4;

typedef const __attribute__((address_space(1))) unsigned int* gas_ptr;
typedef __attribute__((address_space(3))) unsigned int* las_ptr;

__device__ __forceinline__ unsigned short f2b(float f) {
  unsigned int u = __builtin_bit_cast(unsigned int, f);
  return (unsigned short)((u + 0x7fffu + ((u >> 16) & 1u)) >> 16);
}

// ---------------- LayerNorm: f32 in -> bf16 out ----------------
__global__ __launch_bounds__(256) void ln_kernel(const float* __restrict__ x,
                                                 const float* __restrict__ w,
                                                 const float* __restrict__ b,
                                                 unsigned short* __restrict__ out) {
  const int row = blockIdx.x;
  const int t = threadIdx.x;
  const float4 v = *reinterpret_cast<const float4*>(x + (size_t)row * Cn + t * 4);
  float s = v.x + v.y + v.z + v.w;
  float s2 = v.x * v.x + v.y * v.y + v.z * v.z + v.w * v.w;
#pragma unroll
  for (int m = 1; m < 64; m <<= 1) { s += __shfl_xor(s, m); s2 += __shfl_xor(s2, m); }
  __shared__ float ls[4], ls2[4];
  if ((t & 63) == 0) { ls[t >> 6] = s; ls2[t >> 6] = s2; }
  __syncthreads();
  s  = ls[0] + ls[1] + ls[2] + ls[3];
  s2 = ls2[0] + ls2[1] + ls2[2] + ls2[3];
  const float mu = s * (1.0f / Cn);
  const float rstd = rsqrtf(s2 * (1.0f / Cn) - mu * mu + 1e-5f);
  const float4 wv = *reinterpret_cast<const float4*>(w + t * 4);
  const float4 bv = *reinterpret_cast<const float4*>(b + t * 4);
  unsigned short o[4];
  o[0] = f2b((v.x - mu) * rstd * wv.x + bv.x);
  o[1] = f2b((v.y - mu) * rstd * wv.y + bv.y);
  o[2] = f2b((v.z - mu) * rstd * wv.z + bv.z);
  o[3] = f2b((v.w - mu) * rstd * wv.w + bv.w);
  *reinterpret_cast<uint2*>(out + (size_t)row * Cn + t * 4) = *reinterpret_cast<uint2*>(o);
}

// ---------------- Transpose + f32->bf16: W[K][N] -> Wt[N][K] ----------------
__global__ __launch_bounds__(256) void transpose_bf16_kernel(const float* __restrict__ W,
                                                             unsigned short* __restrict__ Wt,
                                                             int K, int N) {
  __shared__ float tile[32][33];
  const int n0 = blockIdx.x * 32, k0 = blockIdx.y * 32;
  const int tx = threadIdx.x & 31, ty = threadIdx.x >> 5;  // ty 0..7
#pragma unroll
  for (int r = 0; r < 4; r++)
    tile[ty + r * 8][tx] = W[(size_t)(k0 + ty + r * 8) * N + n0 + tx];
  __syncthreads();
#pragma unroll
  for (int r = 0; r < 4; r++)
    Wt[(size_t)(n0 + ty + r * 8) * K + k0 + tx] = f2b(tile[tx][ty + r * 8]);
}

// ---------------- 128^2 pipelined GEMM (kept for attn_proj, EP=1) ----------------
template <int EP>
__global__ __launch_bounds__(256) void gemm_kernel(const unsigned short* __restrict__ A,
                                                   const unsigned short* __restrict__ Bt,
                                                   const float* __restrict__ bias,
                                                   const float* res, void* out,
                                                   int M, int N, int K, int nx) {
  __shared__ unsigned short As[3][128 * 32];
  __shared__ unsigned short Bs[3][128 * 32];
  const int tid = threadIdx.x;
  const int lane = tid & 63, w = tid >> 6;
  const int wm = w >> 1, wn = w & 1;
  const int l15 = lane & 15, l4 = lane >> 4;

  const int nwg = gridDim.x;
  int wg = blockIdx.x;
  wg = (wg & 7) * (nwg >> 3) + (wg >> 3);
  const int tile_m = (wg / nx) * 128;
  const int tile_n = (wg % nx) * 128;

  f32x4 acc[4][4] = {};

  const int cbase0 = w * 64 + lane;
  auto stage = [&](int buf, int k0) {
#pragma unroll
    for (int i = 0; i < 2; i++) {
      const int chunk = i * 256 + cbase0;
      const int r = chunk >> 2, c = (chunk & 3) * 8;
      __builtin_amdgcn_global_load_lds(
          (gas_ptr)&A[(size_t)(tile_m + r) * K + k0 + c],
          (las_ptr)&As[buf][(i * 256 + w * 64) * 8], 16, 0, 0);
      __builtin_amdgcn_global_load_lds(
          (gas_ptr)&Bt[(size_t)(tile_n + r) * K + k0 + c],
          (las_ptr)&Bs[buf][(i * 256 + w * 64) * 8], 16, 0, 0);
    }
  };

  stage(0, 0);
  stage(1, 32);
  asm volatile("s_waitcnt vmcnt(4)" ::: "memory");
  __builtin_amdgcn_s_barrier();
  __builtin_amdgcn_sched_barrier(0);

  const int nt = K >> 5;
  for (int t = 0; t < nt; ++t) {
    if (t + 2 < nt) stage((t + 2) % 3, (t + 2) * 32);
    __builtin_amdgcn_sched_barrier(0);

    const int cur = t % 3;
    short8 a[4], b[4];
#pragma unroll
    for (int mi = 0; mi < 4; mi++)
      a[mi] = *reinterpret_cast<const short8*>(&As[cur][(wm * 64 + mi * 16 + l15) * 32 + l4 * 8]);
#pragma unroll
    for (int ni = 0; ni < 4; ni++)
      b[ni] = *reinterpret_cast<const short8*>(&Bs[cur][(wn * 64 + ni * 16 + l15) * 32 + l4 * 8]);
    asm volatile("s_waitcnt lgkmcnt(0)" ::: "memory");
    __builtin_amdgcn_sched_barrier(0);

#pragma unroll
    for (int mi = 0; mi < 4; mi++)
#pragma unroll
      for (int ni = 0; ni < 4; ni++)
        acc[mi][ni] = __builtin_amdgcn_mfma_f32_16x16x32_bf16(a[mi], b[ni], acc[mi][ni], 0, 0, 0);
    __builtin_amdgcn_sched_barrier(0);

    if (t + 2 < nt) {
      asm volatile("s_waitcnt vmcnt(4)" ::: "memory");
    } else {
      asm volatile("s_waitcnt vmcnt(0)" ::: "memory");
    }
    __builtin_amdgcn_s_barrier();
    __builtin_amdgcn_sched_barrier(0);
  }

#pragma unroll
  for (int ni = 0; ni < 4; ni++) {
    const int col = tile_n + wn * 64 + ni * 16 + l15;
    const float bv = bias[col];
#pragma unroll
    for (int mi = 0; mi < 4; mi++) {
#pragma unroll
      for (int r = 0; r < 4; r++) {
        const int row = tile_m + wm * 64 + mi * 16 + l4 * 4 + r;
        const size_t idx = (size_t)row * N + col;
        float v = acc[mi][ni][r] + bv;
        if (EP == 0) {
          ((unsigned short*)out)[idx] = f2b(v);
        } else if (EP == 1) {
          ((float*)out)[idx] = v + res[idx];
        } else {
          float g = 0.5f * v * (1.0f + erff(v * 0.70710678118f));
          ((unsigned short*)out)[idx] = f2b(g);
        }
      }
    }
  }
}

// ---------------- 256^2 8-wave deep-pipelined GEMM (m201-style) ----------------
// BM=BN=256, BK=32, 512 thr = 8 waves (2M x 4N), per-wave C = 128x64 (8x4 frags).
// 4-buffer LDS ring (128 KB dynamic), stage lead 3 tiles, counted vmcnt(8) at tile
// end (tile t+1 proven landed; t+2,t+3 in flight). 2 barrier-aligned MFMA phases
// per tile + setprio (T5). Ordering proofs inline.
// EP=0: bf16 = v+bias; EP=2: bf16 = gelu(v+bias); EP=3: f32 atomicAdd(out, v [+bias if slice0])
#define BUFS 16384   // ushorts per ring slot: A 8192 + B 8192 (32 KB)
template <int EP>
__global__ __launch_bounds__(512, 2) void gemm256_kernel(
    const unsigned short* __restrict__ A, const unsigned short* __restrict__ Bt,
    const float* __restrict__ bias, void* out, int M, int N, int K, int nx, int nk) {
  extern __shared__ unsigned short lds[];
  const int tid = threadIdx.x;
  const int lane = tid & 63, w = tid >> 6;
  const int wm = w >> 2, wn = w & 3;
  const int l15 = lane & 15, l4 = lane >> 4;

  // XCD-aware bijective swizzle (all call sites: gridDim.x % 8 == 0)
  const int nwg = gridDim.x;
  int wg = blockIdx.x;
  wg = (wg & 7) * (nwg >> 3) + (wg >> 3);
  const int ntile = nwg / nk;
  const int slice = wg / ntile;
  const int rem = wg % ntile;
  const int tile_m = (rem / nx) * 256;
  const int tile_n = (rem % nx) * 256;
  const int Klen = K / nk;
  const int kbase = slice * Klen;

  f32x4 acc[8][4] = {};

  // stage one BK=32 K-tile: A 256x32 (16KB) + B 256x32 (16KB); 4 gload_lds/wave.
  // chunk = r*4 + c16; LDS linear == chunk order (wave-uniform base + lane*16B).
  auto stage = [&](int buf, int k0) {
    unsigned short* Ab = lds + buf * BUFS;
    unsigned short* Bb = Ab + 8192;
#pragma unroll
    for (int j = 0; j < 2; j++) {
      const int chunk = j * 512 + w * 64 + lane;
      const int r = chunk >> 2, c = (chunk & 3) * 8;
      __builtin_amdgcn_global_load_lds((gas_ptr)&A[(size_t)(tile_m + r) * K + k0 + c],
                                       (las_ptr)&Ab[(j * 512 + w * 64) * 8], 16, 0, 0);
      __builtin_amdgcn_global_load_lds((gas_ptr)&Bt[(size_t)(tile_n + r) * K + k0 + c],
                                       (las_ptr)&Bb[(j * 512 + w * 64) * 8], 16, 0, 0);
    }
  };

  // prologue: 3 tiles staged (12 loads); wait tile0 (leave 8 in flight)
  stage(0, kbase);
  stage(1, kbase + 32);
  stage(2, kbase + 64);
  asm volatile("s_waitcnt vmcnt(8)" ::: "memory");
  __builtin_amdgcn_s_barrier();
  __builtin_amdgcn_sched_barrier(0);

  const int nt = Klen >> 5;   // 32 at all call sites
  for (int t = 0; t < nt; ++t) {
    // overwrite safety: buf[(t+3)&3] == buf[(t-1)&3]; tile t-1's ds_reads all
    // completed (lgkmcnt(0)) before iter t-1's trailing s_barrier, which this
    // wave has passed before issuing these loads.
    if (t + 3 < nt) stage((t + 3) & 3, kbase + (t + 3) * 32);
    __builtin_amdgcn_sched_barrier(0);

    const unsigned short* Ab = lds + (t & 3) * BUFS;
    const unsigned short* Bb = Ab + 8192;
    short8 a[4], b[4];
    // phase A: mi 0..3 (rows wm*128+..), all ni
#pragma unroll
    for (int i = 0; i < 4; i++) {
      a[i] = *reinterpret_cast<const short8*>(&Ab[(wm * 128 + i * 16 + l15) * 32 + l4 * 8]);
      b[i] = *reinterpret_cast<const short8*>(&Bb[(wn * 64 + i * 16 + l15) * 32 + l4 * 8]);
    }
    __builtin_amdgcn_s_barrier();
    asm volatile("s_waitcnt lgkmcnt(0)" ::: "memory");
    __builtin_amdgcn_sched_barrier(0);    // rule #18
    __builtin_amdgcn_s_setprio(1);
#pragma unroll
    for (int mi = 0; mi < 4; mi++)
#pragma unroll
      for (int ni = 0; ni < 4; ni++)
        acc[mi][ni] = __builtin_amdgcn_mfma_f32_16x16x32_bf16(a[mi], b[ni], acc[mi][ni], 0, 0, 0);
    __builtin_amdgcn_s_setprio(0);
    __builtin_amdgcn_sched_barrier(0);
    __builtin_amdgcn_s_barrier();

    // phase B: mi 4..7, reuse b[]
#pragma unroll
    for (int i = 0; i < 4; i++)
      a[i] = *reinterpret_cast<const short8*>(&Ab[(wm * 128 + 64 + i * 16 + l15) * 32 + l4 * 8]);
    asm volatile("s_waitcnt lgkmcnt(0)" ::: "memory");
    __builtin_amdgcn_sched_barrier(0);
    __builtin_amdgcn_s_setprio(1);
#pragma unroll
    for (int mi = 0; mi < 4; mi++)
#pragma unroll
      for (int ni = 0; ni < 4; ni++)
        acc[mi + 4][ni] = __builtin_amdgcn_mfma_f32_16x16x32_bf16(a[mi], b[ni], acc[mi + 4][ni], 0, 0, 0);
    __builtin_amdgcn_s_setprio(0);
    __builtin_amdgcn_sched_barrier(0);

    // tile end: tile t+1 must be landed. outstanding after wait: t+2,t+3 = 8 loads.
    if (t + 3 < nt) {
      asm volatile("s_waitcnt vmcnt(8)" ::: "memory");
    } else if (t + 2 < nt) {
      asm volatile("s_waitcnt vmcnt(4)" ::: "memory");
    } else if (t + 1 < nt) {
      asm volatile("s_waitcnt vmcnt(0)" ::: "memory");
    }
    __builtin_amdgcn_s_barrier();
    __builtin_amdgcn_sched_barrier(0);
  }

#pragma unroll
  for (int ni = 0; ni < 4; ni++) {
    const int col = tile_n + wn * 64 + ni * 16 + l15;
    float bv = bias[col];
    if (EP == 3 && slice != 0) bv = 0.0f;
#pragma unroll
    for (int mi = 0; mi < 8; mi++) {
#pragma unroll
      for (int r = 0; r < 4; r++) {
        const int row = tile_m + wm * 128 + mi * 16 + l4 * 4 + r;
        const size_t idx = (size_t)row * N + col;
        float v = acc[mi][ni][r] + bv;
        if (EP == 0) {
          ((unsigned short*)out)[idx] = f2b(v);
        } else if (EP == 2) {
          float g = 0.5f * v * (1.0f + erff(v * 0.70710678118f));
          ((unsigned short*)out)[idx] = f2b(g);
        } else {
          atomicAdd(&((float*)out)[idx], v);   // residual already present in out
        }
      }
    }
  }
}

// ---------------- Strided-sparse flash attention ----------------
__global__ __launch_bounds__(256) void attn_kernel(const unsigned short* __restrict__ qkv,
                                                   unsigned short* __restrict__ y) {
  const int qt = blockIdx.x;
  const int bh = blockIdx.y;
  const int bb = bh >> 4, hh = bh & 15;
  const int q0 = qt * 128;
  const int tid = threadIdx.x;
  const int lane = tid & 63, w = tid >> 6;
  const int l15 = lane & 15, l4 = lane >> 4;

  __shared__ unsigned short Qs[128 * 64];
  __shared__ unsigned short Ks[64 * 64];
  __shared__ unsigned short Vt[64 * 72];
  __shared__ unsigned short Ps[4][32 * 72];

  const size_t base = (size_t)bb * Tn * (3 * Cn) + hh * 64;

#pragma unroll
  for (int i = 0; i < 4; i++) {
    const int chunk = i * 256 + tid;
    const int r = chunk >> 3, c = chunk & 7;
    uint4 v = *reinterpret_cast<const uint4*>(&qkv[base + (size_t)(q0 + r) * (3 * Cn) + c * 8]);
    *reinterpret_cast<uint4*>(&Qs[r * 64 + ((c ^ (r & 7)) * 8)]) = v;
  }
  __syncthreads();
  short8 qf[2][2];
#pragma unroll
  for (int mi = 0; mi < 2; mi++)
#pragma unroll
    for (int ks = 0; ks < 2; ks++) {
      const int r = w * 32 + mi * 16 + l15;
      const int c = ks * 4 + l4;
      qf[mi][ks] = *reinterpret_cast<const short8*>(&Qs[r * 64 + ((c ^ (r & 7)) * 8)]);
    }

  f32x4 acc_o[2][4] = {};
  float mrow[2][4], lrow[2][4];
#pragma unroll
  for (int mi = 0; mi < 2; mi++)
#pragma unroll
    for (int r = 0; r < 4; r++) { mrow[mi][r] = -1e30f; lrow[mi][r] = 0.0f; }

  const int nfar = (qt >= 1) ? (qt - 1) : 0;
  const int nstart = (q0 >= 128) ? (q0 - 128) : 0;
  const int ntiles = nfar + (q0 + 128 - nstart) / 64;

  for (int it = 0; it < ntiles; it++) {
    const bool far = (it < nfar);
    const int kbase = far ? it * 128 : nstart + (it - nfar) * 64;
    const int kstride = far ? 2 : 1;

    __syncthreads();
#pragma unroll
    for (int i = 0; i < 2; i++) {
      const int chunk = i * 256 + tid;
      const int r = chunk >> 3, c = chunk & 7;
      const int key = kbase + r * kstride;
      uint4 kv = *reinterpret_cast<const uint4*>(&qkv[base + Cn + (size_t)key * (3 * Cn) + c * 8]);
      *reinterpret_cast<uint4*>(&Ks[r * 64 + ((c ^ (r & 7)) * 8)]) = kv;
      uint4 vv = *reinterpret_cast<const uint4*>(&qkv[base + 2 * Cn + (size_t)key * (3 * Cn) + c * 8]);
      unsigned short tmp[8];
      *reinterpret_cast<uint4*>(tmp) = vv;
#pragma unroll
      for (int j = 0; j < 8; j++) Vt[(c * 8 + j) * 72 + r] = tmp[j];
    }
    __syncthreads();

    f32x4 s[2][4] = {};
#pragma unroll
    for (int ni = 0; ni < 4; ni++) {
#pragma unroll
      for (int ks = 0; ks < 2; ks++) {
        const int r = ni * 16 + l15;
        const int c = ks * 4 + l4;
        short8 kf = *reinterpret_cast<const short8*>(&Ks[r * 64 + ((c ^ (r & 7)) * 8)]);
#pragma unroll
        for (int mi = 0; mi < 2; mi++)
          s[mi][ni] = __builtin_amdgcn_mfma_f32_16x16x32_bf16(qf[mi][ks], kf, s[mi][ni], 0, 0, 0);
      }
    }

#pragma unroll
    for (int mi = 0; mi < 2; mi++)
#pragma unroll
      for (int ni = 0; ni < 4; ni++) {
        const int j = kbase + (ni * 16 + l15) * kstride;
#pragma unroll
        for (int r = 0; r < 4; r++) {
          const int iq = q0 + w * 32 + mi * 16 + l4 * 4 + r;
          float v = s[mi][ni][r] * 0.125f;
          if (!far) {
            const bool ok = (j <= iq) && ((j >= iq - 4) || ((j & 1) == 0));
            v = ok ? v : -1e30f;
          }
          s[mi][ni][r] = v;
        }
      }

#pragma unroll
    for (int mi = 0; mi < 2; mi++)
#pragma unroll
      for (int r = 0; r < 4; r++) {
        float tm = fmaxf(fmaxf(s[mi][0][r], s[mi][1][r]), fmaxf(s[mi][2][r], s[mi][3][r]));
        tm = fmaxf(tm, __shfl_xor(tm, 1));
        tm = fmaxf(tm, __shfl_xor(tm, 2));
        tm = fmaxf(tm, __shfl_xor(tm, 4));
        tm = fmaxf(tm, __shfl_xor(tm, 8));
        const float mnew = fmaxf(mrow[mi][r], tm);
        const float alpha = __expf(mrow[mi][r] - mnew);
        mrow[mi][r] = mnew;
        lrow[mi][r] *= alpha;
#pragma unroll
        for (int nd = 0; nd < 4; nd++) acc_o[mi][nd][r] *= alpha;
        float rs = 0.0f;
#pragma unroll
        for (int ni = 0; ni < 4; ni++) {
          const float p = __expf(s[mi][ni][r] - mnew);
          s[mi][ni][r] = p;
          rs += p;
        }
        rs += __shfl_xor(rs, 1); rs += __shfl_xor(rs, 2);
        rs += __shfl_xor(rs, 4); rs += __shfl_xor(rs, 8);
        lrow[mi][r] += rs;
      }

#pragma unroll
    for (int mi = 0; mi < 2; mi++)
#pragma unroll
      for (int ni = 0; ni < 4; ni++)
#pragma unroll
        for (int r = 0; r < 4; r++)
          Ps[w][(mi * 16 + l4 * 4 + r) * 72 + ni * 16 + l15] = f2b(s[mi][ni][r]);

#pragma unroll
    for (int ks = 0; ks < 2; ks++) {
      short8 pf[2];
#pragma unroll
      for (int mi = 0; mi < 2; mi++)
        pf[mi] = *reinterpret_cast<const short8*>(&Ps[w][(mi * 16 + l15) * 72 + ks * 32 + l4 * 8]);
#pragma unroll
      for (int nd = 0; nd < 4; nd++) {
        short8 vf = *reinterpret_cast<const short8*>(&Vt[(nd * 16 + l15) * 72 + ks * 32 + l4 * 8]);
#pragma unroll
        for (int mi = 0; mi < 2; mi++)
          acc_o[mi][nd] = __builtin_amdgcn_mfma_f32_16x16x32_bf16(pf[mi], vf, acc_o[mi][nd], 0, 0, 0);
      }
    }
  }

#pragma unroll
  for (int mi = 0; mi < 2; mi++)
#pragma unroll
    for (int r = 0; r < 4; r++) {
      const float inv = 1.0f / lrow[mi][r];
      const int row = q0 + w * 32 + mi * 16 + l4 * 4 + r;
#pragma unroll
      for (int nd = 0; nd < 4; nd++) {
        const int col = nd * 16 + l15;
        y[((size_t)bb * Tn + row) * Cn + hh * 64 + col] = f2b(acc_o[mi][nd][r] * inv);
      }
    }
}

// ---------------- launch ----------------
extern "C" void kernel_launch(void* const* d_in, const int* in_sizes, int n_in,
                              void* d_out, int out_size, void* d_ws, size_t ws_size,
                              hipStream_t stream) {
  const float* x           = (const float*)d_in[0];
  const float* ln1_w       = (const float*)d_in[1];
  const float* ln1_b       = (const float*)d_in[2];
  const float* c_attn_w    = (const float*)d_in[3];
  const float* c_attn_b    = (const float*)d_in[4];
  const float* attn_proj_w = (const float*)d_in[5];
  const float* attn_proj_b = (const float*)d_in[6];
  const float* ln2_w       = (const float*)d_in[7];
  const float* ln2_b       = (const float*)d_in[8];
  const float* fc_w        = (const float*)d_in[9];
  const float* fc_b        = (const float*)d_in[10];
  const float* mlp_proj_w  = (const float*)d_in[11];
  const float* mlp_proj_b  = (const float*)d_in[12];
  float* out = (float*)d_out;

  char* ws = (char*)d_ws;
  unsigned short* wT1 = (unsigned short*)(ws);                     // [3072][1024]
  unsigned short* wT2 = (unsigned short*)(ws + 6291456);           // [1024][1024]
  unsigned short* wT3 = (unsigned short*)(ws + 8388608);           // [4096][1024]
  unsigned short* wT4 = (unsigned short*)(ws + 16777216);          // [1024][4096]
  unsigned short* h   = (unsigned short*)(ws + 25165824);          // [4096][1024]
  unsigned short* qkv = (unsigned short*)(ws + 33554432);          // [4096][3072] / [4096][4096]
  unsigned short* yb  = (unsigned short*)(ws + 67108864);          // [4096][1024]

  // enable 128 KB dynamic LDS for the 256^2 kernels (idempotent)
  hipFuncSetAttribute((const void*)gemm256_kernel<0>, hipFuncAttributeMaxDynamicSharedMemorySize, 131072);
  hipFuncSetAttribute((const void*)gemm256_kernel<2>, hipFuncAttributeMaxDynamicSharedMemorySize, 131072);
  hipFuncSetAttribute((const void*)gemm256_kernel<3>, hipFuncAttributeMaxDynamicSharedMemorySize, 131072);

  // weight transposes (f32 -> bf16, [K][N] -> [N][K])
  transpose_bf16_kernel<<<dim3(3072 / 32, 1024 / 32), 256, 0, stream>>>(c_attn_w, wT1, 1024, 3072);
  transpose_bf16_kernel<<<dim3(1024 / 32, 1024 / 32), 256, 0, stream>>>(attn_proj_w, wT2, 1024, 1024);
  transpose_bf16_kernel<<<dim3(4096 / 32, 1024 / 32), 256, 0, stream>>>(fc_w, wT3, 1024, 4096);
  transpose_bf16_kernel<<<dim3(1024 / 32, 4096 / 32), 256, 0, stream>>>(mlp_proj_w, wT4, 4096, 1024);

  // LN1
  ln_kernel<<<Mrows, 256, 0, stream>>>(x, ln1_w, ln1_b, h);
  // qkv = h @ c_attn_w + b   [4096, 3072]   grid 16x12 = 192
  gemm256_kernel<0><<<(Mrows / 256) * (3072 / 256), 512, 131072, stream>>>(
      h, wT1, c_attn_b, qkv, Mrows, 3072, 1024, 3072 / 256, 1);
  // attention -> y
  attn_kernel<<<dim3(Tn / 128, Bn * Hn), 256, 0, stream>>>(qkv, yb);
  // x1 = x + y @ attn_proj_w + b  -> d_out (f32) — overwrite-write resets out each replay
  gemm_kernel<1><<<(1024 / 128) * (Mrows / 128), 256, 0, stream>>>(yb, wT2, attn_proj_b, x, out, Mrows, 1024, 1024, 1024 / 128);
  // LN2 on x1
  ln_kernel<<<Mrows, 256, 0, stream>>>(out, ln2_w, ln2_b, h);
  // a = gelu(h2 @ fc_w + b)   [4096, 4096]   grid 16x16 = 256
  gemm256_kernel<2><<<(Mrows / 256) * (4096 / 256), 512, 131072, stream>>>(
      h, wT3, fc_b, qkv, Mrows, 4096, 1024, 4096 / 256, 1);
  // out += a @ mlp_proj_w + b   split-K=4, grid 64*4 = 256, atomicAdd epilogue
  gemm256_kernel<3><<<(Mrows / 256) * (1024 / 256) * 4, 512, 131072, stream>>>(
      qkv, wT4, mlp_proj_b, out, Mrows, 1024, 4096, 1024 / 256, 4);
}